// Round 1
// baseline (309.266 us; speedup 1.0000x reference)
//
#include <hip/hip_runtime.h>
#include <hip/hip_bf16.h>

// Problem constants (from reference)
#define NB   16384   // batch B
#define KNEG 32      // negatives per sample
#define LQ   256     // LATENT
#define LACT 64      // ACT
#define HD   128     // H
#define QN   65536   // queue size
#define EPS_ 0.01f   // label smoothing

__device__ __forceinline__ float san(float x) { return isfinite(x) ? x : 0.0f; }

// Fused 2-layer MLP: out[N,128] = relu(X[N,L] @ W1[L,128] + b1) @ W2[128,128] + b2
// Block: 256 threads, TILE=32 rows. Thread (rg=tid>>5, jc=tid&31) computes a
// 4x4 register tile (rows rg*4.., cols jc*4..). LDS reads are float4 along the
// K dim so the inner loop is FMA-bound, not ds_read-bound.
template<int L>
__global__ __launch_bounds__(256) void mlp_kernel(
    const float* __restrict__ X,  const float* __restrict__ W1,
    const float* __restrict__ b1, const float* __restrict__ W2,
    const float* __restrict__ b2, float* __restrict__ out)
{
    constexpr int TILE = 32;
    __shared__ __align__(16) float xs[TILE * L];      // input tile (sanitized)
    __shared__ __align__(16) float hs[TILE * HD];     // hidden tile (relu'd)

    const int tid = threadIdx.x;
    const int jc  = tid & 31;   // column group: cols jc*4 .. jc*4+3
    const int rg  = tid >> 5;   // row group:    rows rg*4 .. rg*4+3
    const long base = (long)blockIdx.x * TILE;

    // ---- stage X tile (coalesced float4, sanitize) ----
    const float4* Xv = (const float4*)(X + base * L);
    float4* xsv = (float4*)xs;
    #pragma unroll
    for (int i = tid; i < TILE * L / 4; i += 256) {
        float4 v = Xv[i];
        v.x = san(v.x); v.y = san(v.y); v.z = san(v.z); v.w = san(v.w);
        xsv[i] = v;
    }
    __syncthreads();

    // ---- layer 1: acc[4][4] = X_tile @ W1 ----
    float acc[4][4];
    #pragma unroll
    for (int r = 0; r < 4; ++r)
        #pragma unroll
        for (int c = 0; c < 4; ++c) acc[r][c] = 0.0f;

    for (int l0 = 0; l0 < L; l0 += 4) {
        float4 xr[4], wr[4];
        #pragma unroll
        for (int rr = 0; rr < 4; ++rr)
            xr[rr] = *(const float4*)&xs[(rg * 4 + rr) * L + l0];
        #pragma unroll
        for (int ll = 0; ll < 4; ++ll)
            wr[ll] = *(const float4*)&W1[(l0 + ll) * HD + jc * 4];
        #pragma unroll
        for (int rr = 0; rr < 4; ++rr) {
            const float xv[4] = {xr[rr].x, xr[rr].y, xr[rr].z, xr[rr].w};
            #pragma unroll
            for (int ll = 0; ll < 4; ++ll) {
                acc[rr][0] = fmaf(xv[ll], wr[ll].x, acc[rr][0]);
                acc[rr][1] = fmaf(xv[ll], wr[ll].y, acc[rr][1]);
                acc[rr][2] = fmaf(xv[ll], wr[ll].z, acc[rr][2]);
                acc[rr][3] = fmaf(xv[ll], wr[ll].w, acc[rr][3]);
            }
        }
    }

    const float4 bb1 = *(const float4*)&b1[jc * 4];
    #pragma unroll
    for (int rr = 0; rr < 4; ++rr) {
        float4 h;
        h.x = fmaxf(acc[rr][0] + bb1.x, 0.0f);
        h.y = fmaxf(acc[rr][1] + bb1.y, 0.0f);
        h.z = fmaxf(acc[rr][2] + bb1.z, 0.0f);
        h.w = fmaxf(acc[rr][3] + bb1.w, 0.0f);
        *(float4*)&hs[(rg * 4 + rr) * HD + jc * 4] = h;
    }
    __syncthreads();

    // ---- layer 2: out = relu_h @ W2 ----
    #pragma unroll
    for (int r = 0; r < 4; ++r)
        #pragma unroll
        for (int c = 0; c < 4; ++c) acc[r][c] = 0.0f;

    for (int k0 = 0; k0 < HD; k0 += 4) {
        float4 xr[4], wr[4];
        #pragma unroll
        for (int rr = 0; rr < 4; ++rr)
            xr[rr] = *(const float4*)&hs[(rg * 4 + rr) * HD + k0];
        #pragma unroll
        for (int kk = 0; kk < 4; ++kk)
            wr[kk] = *(const float4*)&W2[(k0 + kk) * HD + jc * 4];
        #pragma unroll
        for (int rr = 0; rr < 4; ++rr) {
            const float xv[4] = {xr[rr].x, xr[rr].y, xr[rr].z, xr[rr].w};
            #pragma unroll
            for (int kk = 0; kk < 4; ++kk) {
                acc[rr][0] = fmaf(xv[kk], wr[kk].x, acc[rr][0]);
                acc[rr][1] = fmaf(xv[kk], wr[kk].y, acc[rr][1]);
                acc[rr][2] = fmaf(xv[kk], wr[kk].z, acc[rr][2]);
                acc[rr][3] = fmaf(xv[kk], wr[kk].w, acc[rr][3]);
            }
        }
    }

    const float4 bb2 = *(const float4*)&b2[jc * 4];
    #pragma unroll
    for (int rr = 0; rr < 4; ++rr) {
        float4 o;
        o.x = san(acc[rr][0] + bb2.x);
        o.y = san(acc[rr][1] + bb2.y);
        o.z = san(acc[rr][2] + bb2.z);
        o.w = san(acc[rr][3] + bb2.w);
        *(float4*)&out[(base + rg * 4 + rr) * HD + jc * 4] = o;
    }
}

// Loss kernel: one 64-lane wave per batch row. Lane n (n<33) owns logit n
// (n=0: emb_l, n>=1: gathered negative). Per-lane float4 dot over 128 dims;
// rows are 512B contiguous so L1 line reuse across the d4 loop is full.
// Softmax via 64-wide butterfly shuffles.
__global__ __launch_bounds__(256) void loss_kernel(
    const float* __restrict__ emb_a, const float* __restrict__ emb_l,
    const float* __restrict__ proj_q, const int* __restrict__ neg_idx,
    const float* __restrict__ temp_p, float* __restrict__ out)
{
    __shared__ float4 eas[4][32];
    __shared__ int    nidx[4][32];

    const int tid  = threadIdx.x;
    const int w    = tid >> 6;     // wave in block (0..3)
    const int lane = tid & 63;
    const long b   = (long)blockIdx.x * 4 + w;

    // temperature: nan_to_num(t, 0.1) then clip [0.01, 10]
    float t = temp_p[0];
    if (!isfinite(t)) t = 0.1f;
    t = fminf(fmaxf(t, 0.01f), 10.0f);
    const float invt = 1.0f / t;

    if (lane < 32) {
        eas[w][lane]  = ((const float4*)emb_a)[b * 32 + lane];
        nidx[w][lane] = neg_idx[b * KNEG + lane];
    }
    __syncthreads();

    // pointer to this lane's latent row
    const float* lat;
    if (lane == 0)       lat = emb_l + b * HD;
    else if (lane <= 32) lat = proj_q + (long)nidx[w][lane - 1] * HD;
    else                 lat = emb_l + b * HD;   // dummy (masked out)

    const float4* lat4 = (const float4*)lat;
    float acc = 0.0f;
    #pragma unroll
    for (int d4 = 0; d4 < 32; ++d4) {
        float4 v = lat4[d4];
        float4 a = eas[w][d4];
        acc = fmaf(v.x, a.x, acc);
        acc = fmaf(v.y, a.y, acc);
        acc = fmaf(v.z, a.z, acc);
        acc = fmaf(v.w, a.w, acc);
    }

    const bool valid = (lane < 33);
    float lg = valid ? fminf(fmaxf(san(acc * invt), -20.0f), 20.0f) : 0.0f;

    // max over valid lanes
    float m = valid ? lg : -1e30f;
    #pragma unroll
    for (int off = 1; off < 64; off <<= 1)
        m = fmaxf(m, __shfl_xor(m, off, 64));

    // sum of exp and sum of logits over valid lanes
    float e  = valid ? expf(lg - m) : 0.0f;
    float sl = valid ? lg : 0.0f;
    #pragma unroll
    for (int off = 1; off < 64; off <<= 1) {
        e  += __shfl_xor(e, off, 64);
        sl += __shfl_xor(sl, off, 64);
    }

    const float l0 = __shfl(lg, 0, 64);

    // loss = (m + logS) - (1-eps)*logit0 - eps*mean(logits)
    float loss = (m + logf(e)) - (1.0f - EPS_) * l0 - EPS_ * (sl * (1.0f / 33.0f));
    loss = fminf(fmaxf(san(loss), -10.0f), 10.0f);

    if (lane == 0) out[b] = -loss;
}

extern "C" void kernel_launch(void* const* d_in, const int* in_sizes, int n_in,
                              void* d_out, int out_size, void* d_ws, size_t ws_size,
                              hipStream_t stream) {
    const float* action  = (const float*)d_in[0];
    const float* latent  = (const float*)d_in[1];
    const float* queue   = (const float*)d_in[2];
    const int*   neg_idx = (const int*)  d_in[3];
    const float* a_w1    = (const float*)d_in[4];
    const float* a_b1    = (const float*)d_in[5];
    const float* a_w2    = (const float*)d_in[6];
    const float* a_b2    = (const float*)d_in[7];
    const float* l_w1    = (const float*)d_in[8];
    const float* l_b1    = (const float*)d_in[9];
    const float* l_w2    = (const float*)d_in[10];
    const float* l_b2    = (const float*)d_in[11];
    const float* temp    = (const float*)d_in[12];
    float* out = (float*)d_out;

    // workspace: emb_a [B,128] f32 (8MB) | emb_l [B,128] f32 (8MB) | proj_q [Q,128] f32 (32MB)
    float* emb_a  = (float*)d_ws;
    float* emb_l  = emb_a + (size_t)NB * HD;
    float* proj_q = emb_l + (size_t)NB * HD;

    mlp_kernel<LACT><<<NB / 32, 256, 0, stream>>>(action, a_w1, a_b1, a_w2, a_b2, emb_a);
    mlp_kernel<LQ>  <<<NB / 32, 256, 0, stream>>>(latent, l_w1, l_b1, l_w2, l_b2, emb_l);
    mlp_kernel<LQ>  <<<QN / 32, 256, 0, stream>>>(queue,  l_w1, l_b1, l_w2, l_b2, proj_q);
    loss_kernel<<<NB / 4, 256, 0, stream>>>(emb_a, emb_l, proj_q, neg_idx, temp, out);
}

// Round 2
// 231.483 us; speedup vs baseline: 1.3360x; 1.3360x over previous
//
#include <hip/hip_runtime.h>
#include <hip/hip_bf16.h>

// Problem constants (from reference)
#define NB   16384   // batch B
#define KNEG 32      // negatives per sample
#define LQ   256     // LATENT
#define LACT 64      // ACT
#define HD   128     // H
#define QN   65536   // queue size
#define EPS_ 0.01f   // label smoothing

typedef __attribute__((ext_vector_type(8))) short s16x8;   // 8 bf16 (4 VGPRs) MFMA frag
typedef __attribute__((ext_vector_type(4))) float f32x4;   // MFMA accumulator

__device__ __forceinline__ float san(float x) { return isfinite(x) ? x : 0.0f; }

// fp32 -> bf16 bits, round-to-nearest-even (inputs are pre-sanitized, no NaN path)
__device__ __forceinline__ ushort bfbits(float f) {
    uint u = __builtin_bit_cast(uint, f);
    u += 0x7FFFu + ((u >> 16) & 1u);
    return (ushort)(u >> 16);
}
__device__ __forceinline__ float bf2f(ushort h) {
    uint u = ((uint)h) << 16;
    return __builtin_bit_cast(float, u);
}

// One-time: transpose + bf16-convert the 4 weight matrices so MFMA A-operands
// (W^T rows) are contiguous along K. 73728 elements total -> trivial cost.
__global__ __launch_bounds__(256) void prep_weights(
    const float* __restrict__ aw1, const float* __restrict__ aw2,
    const float* __restrict__ lw1, const float* __restrict__ lw2,
    ushort* __restrict__ aw1T, ushort* __restrict__ aw2T,
    ushort* __restrict__ lw1T, ushort* __restrict__ lw2T)
{
    int idx = blockIdx.x * 256 + threadIdx.x;
    if (idx < 8192) {                       // a_w1 [64][128] -> [128][64]
        int r = idx >> 7, c = idx & 127;
        aw1T[c * 64 + r] = bfbits(aw1[idx]);
    } else if (idx < 24576) {               // a_w2 [128][128] -> [128][128]
        int e = idx - 8192, r = e >> 7, c = e & 127;
        aw2T[c * 128 + r] = bfbits(aw2[e]);
    } else if (idx < 57344) {               // l_w1 [256][128] -> [128][256]
        int e = idx - 24576, r = e >> 7, c = e & 127;
        lw1T[c * 256 + r] = bfbits(lw1[e]);
    } else {                                // l_w2 [128][128] -> [128][128]
        int e = idx - 57344, r = e >> 7, c = e & 127;
        lw2T[c * 128 + r] = bfbits(lw2[e]);
    }
}

// MFMA MLP: out[N,128](bf16) = relu(X@W1+b1)@W2 + b2, computed transposed:
//   layer1: D1 = W1T(128xL) x X^T(Lx16)   -> lane holds H^T[16mt+4g+r][c]
//   layer2: D2 = W2T(128x128) x H(128x16) -> lane holds O^T[16mt+4g+r][c]
// Wave = 16 rows; block = 4 waves = 64 rows. Layouts (16x16x32 bf16 MFMA):
//   A-frag: lane l holds A[l&15][(l>>4)*8+i]  -> contiguous K in W^T rows
//   B-frag: lane l holds B[(l>>4)*8+i][l&15]  -> contiguous K in X / H rows
//   D-frag: lane l holds D[(l>>4)*4+r][l&15]
// H round-trips through a per-wave 4KB LDS tile [16 rows][128] bf16 with a
// byte XOR-swizzle (off ^= 16*(c&7)): ds_write_b64 / ds_read_b128 both land
// 2-way per bank (free) instead of 16-way.
template<int L>
__global__ __launch_bounds__(256) void mlp_mfma(
    const float* __restrict__ X,  const ushort* __restrict__ W1T,
    const float* __restrict__ b1, const ushort* __restrict__ W2T,
    const float* __restrict__ b2, ushort* __restrict__ out)
{
    __shared__ ushort hsm[4][2048];   // per-wave hidden tile, swizzled

    const int tid  = threadIdx.x;
    const int w    = tid >> 6;
    const int lane = tid & 63;
    const int g    = lane >> 4;       // k-group 0..3
    const int c    = lane & 15;       // row-in-tile / col-in-frag
    const long row = (long)blockIdx.x * 64 + w * 16 + c;

    // ---- layer 1 ----
    f32x4 acc[8];
    #pragma unroll
    for (int mt = 0; mt < 8; ++mt) acc[mt] = (f32x4)(0.0f);

    const float* xrow = X + row * L;
    for (int ks = 0; ks < L / 32; ++ks) {
        // B-frag: X[row][32ks+8g .. +7], sanitize + cvt to bf16
        float4 xa = *(const float4*)(xrow + 32 * ks + 8 * g);
        float4 xb = *(const float4*)(xrow + 32 * ks + 8 * g + 4);
        s16x8 bx;
        bx[0] = (short)bfbits(san(xa.x)); bx[1] = (short)bfbits(san(xa.y));
        bx[2] = (short)bfbits(san(xa.z)); bx[3] = (short)bfbits(san(xa.w));
        bx[4] = (short)bfbits(san(xb.x)); bx[5] = (short)bfbits(san(xb.y));
        bx[6] = (short)bfbits(san(xb.z)); bx[7] = (short)bfbits(san(xb.w));
        #pragma unroll
        for (int mt = 0; mt < 8; ++mt) {
            s16x8 af = *(const s16x8*)(W1T + (16 * mt + c) * L + 32 * ks + 8 * g);
            acc[mt] = __builtin_amdgcn_mfma_f32_16x16x32_bf16(af, bx, acc[mt], 0, 0, 0);
        }
    }

    // bias + relu + pack -> swizzled LDS (H[row c][hidden 16mt+4g+r])
    char* hb = (char*)&hsm[w][0];
    #pragma unroll
    for (int mt = 0; mt < 8; ++mt) {
        float4 bb = *(const float4*)(b1 + 16 * mt + 4 * g);
        ushort4 hv;
        hv.x = bfbits(fmaxf(acc[mt][0] + bb.x, 0.0f));
        hv.y = bfbits(fmaxf(acc[mt][1] + bb.y, 0.0f));
        hv.z = bfbits(fmaxf(acc[mt][2] + bb.z, 0.0f));
        hv.w = bfbits(fmaxf(acc[mt][3] + bb.w, 0.0f));
        int off = (32 * mt + 8 * g) ^ (16 * (c & 7));
        *(ushort4*)(hb + c * 256 + off) = hv;
    }
    __syncthreads();

    // ---- layer 2 ----
    f32x4 acc2[8];
    #pragma unroll
    for (int mt = 0; mt < 8; ++mt) acc2[mt] = (f32x4)(0.0f);

    #pragma unroll
    for (int ks = 0; ks < 4; ++ks) {
        int off = (64 * ks + 16 * g) ^ (16 * (c & 7));
        s16x8 hfrag = *(const s16x8*)(hb + c * 256 + off);
        #pragma unroll
        for (int mt = 0; mt < 8; ++mt) {
            s16x8 af = *(const s16x8*)(W2T + (16 * mt + c) * HD + 32 * ks + 8 * g);
            acc2[mt] = __builtin_amdgcn_mfma_f32_16x16x32_bf16(af, hfrag, acc2[mt], 0, 0, 0);
        }
    }

    // epilogue: O^T[ocol=16mt+4g+r][row c] -> out[row][ocol], 4 consecutive ocols
    ushort* orow = out + row * HD;
    #pragma unroll
    for (int mt = 0; mt < 8; ++mt) {
        float4 bb = *(const float4*)(b2 + 16 * mt + 4 * g);
        ushort4 ov;
        ov.x = bfbits(san(acc2[mt][0] + bb.x));
        ov.y = bfbits(san(acc2[mt][1] + bb.y));
        ov.z = bfbits(san(acc2[mt][2] + bb.z));
        ov.w = bfbits(san(acc2[mt][3] + bb.w));
        *(ushort4*)(orow + 16 * mt + 4 * g) = ov;
    }
}

// Loss: one wave per batch row; lane n<33 owns logit n (0: emb_l, else gathered
// negative). bf16 rows (256B) halve gather traffic vs fp32; dot in fp32.
__global__ __launch_bounds__(256) void loss_kernel(
    const ushort* __restrict__ emb_a, const ushort* __restrict__ emb_l,
    const ushort* __restrict__ proj_q, const int* __restrict__ neg_idx,
    const float* __restrict__ temp_p, float* __restrict__ out)
{
    __shared__ float eas[4][128];
    __shared__ int   nidx[4][32];

    const int tid  = threadIdx.x;
    const int w    = tid >> 6;
    const int lane = tid & 63;
    const long b   = (long)blockIdx.x * 4 + w;

    float t = temp_p[0];
    if (!isfinite(t)) t = 0.1f;
    t = fminf(fmaxf(t, 0.01f), 10.0f);
    const float invt = 1.0f / t;

    if (lane < 32) {
        ushort4 v = ((const ushort4*)(emb_a + b * HD))[lane];
        eas[w][lane * 4 + 0] = bf2f(v.x);
        eas[w][lane * 4 + 1] = bf2f(v.y);
        eas[w][lane * 4 + 2] = bf2f(v.z);
        eas[w][lane * 4 + 3] = bf2f(v.w);
        nidx[w][lane] = neg_idx[b * KNEG + lane];
    }
    __syncthreads();

    const ushort* lat;
    if (lane == 0)       lat = emb_l + b * HD;
    else if (lane <= 32) lat = proj_q + (long)nidx[w][lane - 1] * HD;
    else                 lat = emb_l + b * HD;   // dummy (masked out)

    float acc = 0.0f;
    #pragma unroll
    for (int i = 0; i < 16; ++i) {
        s16x8 lv = *(const s16x8*)(lat + i * 8);
        #pragma unroll
        for (int j = 0; j < 8; ++j)
            acc = fmaf(bf2f((ushort)lv[j]), eas[w][i * 8 + j], acc);
    }

    const bool valid = (lane < 33);
    float lg = valid ? fminf(fmaxf(san(acc * invt), -20.0f), 20.0f) : 0.0f;

    float m = valid ? lg : -1e30f;
    #pragma unroll
    for (int off = 1; off < 64; off <<= 1)
        m = fmaxf(m, __shfl_xor(m, off, 64));

    float e  = valid ? expf(lg - m) : 0.0f;
    float sl = valid ? lg : 0.0f;
    #pragma unroll
    for (int off = 1; off < 64; off <<= 1) {
        e  += __shfl_xor(e, off, 64);
        sl += __shfl_xor(sl, off, 64);
    }

    const float l0 = __shfl(lg, 0, 64);

    float loss = (m + logf(e)) - (1.0f - EPS_) * l0 - EPS_ * (sl * (1.0f / 33.0f));
    loss = fminf(fmaxf(san(loss), -10.0f), 10.0f);

    if (lane == 0) out[b] = -loss;
}

extern "C" void kernel_launch(void* const* d_in, const int* in_sizes, int n_in,
                              void* d_out, int out_size, void* d_ws, size_t ws_size,
                              hipStream_t stream) {
    const float* action  = (const float*)d_in[0];
    const float* latent  = (const float*)d_in[1];
    const float* queue   = (const float*)d_in[2];
    const int*   neg_idx = (const int*)  d_in[3];
    const float* a_w1    = (const float*)d_in[4];
    const float* a_b1    = (const float*)d_in[5];
    const float* a_w2    = (const float*)d_in[6];
    const float* a_b2    = (const float*)d_in[7];
    const float* l_w1    = (const float*)d_in[8];
    const float* l_b1    = (const float*)d_in[9];
    const float* l_w2    = (const float*)d_in[10];
    const float* l_b2    = (const float*)d_in[11];
    const float* temp    = (const float*)d_in[12];
    float* out = (float*)d_out;

    // ws: emb_a bf16 4MB | emb_l bf16 4MB | proj_q bf16 16MB | w-transposes 144KB
    ushort* emb_a  = (ushort*)d_ws;
    ushort* emb_l  = emb_a + (size_t)NB * HD;
    ushort* proj_q = emb_l + (size_t)NB * HD;
    ushort* aw1T   = proj_q + (size_t)QN * HD;
    ushort* aw2T   = aw1T + 128 * 64;
    ushort* lw1T   = aw2T + 128 * 128;
    ushort* lw2T   = lw1T + 128 * 256;

    prep_weights<<<288, 256, 0, stream>>>(a_w1, a_w2, l_w1, l_w2, aw1T, aw2T, lw1T, lw2T);
    mlp_mfma<LACT><<<NB / 64, 256, 0, stream>>>(action, aw1T, a_b1, aw2T, a_b2, emb_a);
    mlp_mfma<LQ>  <<<NB / 64, 256, 0, stream>>>(latent, lw1T, l_b1, lw2T, l_b2, emb_l);
    mlp_mfma<LQ>  <<<QN / 64, 256, 0, stream>>>(queue,  lw1T, l_b1, lw2T, l_b2, proj_q);
    loss_kernel<<<NB / 4, 256, 0, stream>>>(emb_a, emb_l, proj_q, neg_idx, temp, out);
}

// Round 3
// 207.763 us; speedup vs baseline: 1.4885x; 1.1142x over previous
//
#include <hip/hip_runtime.h>
#include <hip/hip_bf16.h>

// Problem constants (from reference)
#define NB   16384   // batch B
#define KNEG 32      // negatives per sample
#define LQ   256     // LATENT
#define LACT 64      // ACT
#define HD   128     // H
#define QN   65536   // queue size
#define EPS_ 0.01f   // label smoothing

typedef __attribute__((ext_vector_type(8))) short s16x8;   // 8 bf16 (4 VGPRs) MFMA frag
typedef __attribute__((ext_vector_type(4))) float f32x4;   // MFMA accumulator

__device__ __forceinline__ float san(float x) { return isfinite(x) ? x : 0.0f; }

// fp32 -> bf16 bits, round-to-nearest-even (inputs are pre-sanitized)
__device__ __forceinline__ ushort bfbits(float f) {
    uint u = __builtin_bit_cast(uint, f);
    u += 0x7FFFu + ((u >> 16) & 1u);
    return (ushort)(u >> 16);
}
__device__ __forceinline__ float bf2f(ushort h) {
    uint u = ((uint)h) << 16;
    return __builtin_bit_cast(float, u);
}

// One-time: transpose + bf16-convert the 4 weight matrices so MFMA A-operands
// (W^T rows) are contiguous along K. 73728 elements -> trivial cost.
__global__ __launch_bounds__(256) void prep_weights(
    const float* __restrict__ aw1, const float* __restrict__ aw2,
    const float* __restrict__ lw1, const float* __restrict__ lw2,
    ushort* __restrict__ aw1T, ushort* __restrict__ aw2T,
    ushort* __restrict__ lw1T, ushort* __restrict__ lw2T)
{
    int idx = blockIdx.x * 256 + threadIdx.x;
    if (idx < 8192) {                       // a_w1 [64][128] -> [128][64]
        int r = idx >> 7, c = idx & 127;
        aw1T[c * 64 + r] = bfbits(aw1[idx]);
    } else if (idx < 24576) {               // a_w2 [128][128] -> [128][128]
        int e = idx - 8192, r = e >> 7, c = e & 127;
        aw2T[c * 128 + r] = bfbits(aw2[e]);
    } else if (idx < 57344) {               // l_w1 [256][128] -> [128][256]
        int e = idx - 24576, r = e >> 7, c = e & 127;
        lw1T[c * 256 + r] = bfbits(lw1[e]);
    } else {                                // l_w2 [128][128] -> [128][128]
        int e = idx - 57344, r = e >> 7, c = e & 127;
        lw2T[c * 128 + r] = bfbits(lw2[e]);
    }
}

// MLP tile (transposed compute, 16x16x32 bf16 MFMA):
//   layer1: D1 = W1T(128xL) x X^T(L x 32rows), layer2: D2 = W2T x H.
// Wave handles 2 row-groups of 16 rows (32 rows); block = 4 waves = 128 rows.
// Weight frags are reused across both row-groups: per K-step 12 VMEM -> 16 MFMA.
// Fragments: A lane l: A[l&15][(l>>4)*8+i]; B lane l: B[(l>>4)*8+i][l&15];
//            D lane l: D[(l>>4)*4+r][l&15].
// H round-trips through a per-wave 8KB LDS tile [32 rows][128] bf16 with byte
// XOR-swizzle (off ^= 16*(c&7)) so ds_write_b64/ds_read_b128 are ~2-way.
template<int L>
__device__ __forceinline__ void mlp_tile(
    const float* __restrict__ Xt,  const ushort* __restrict__ W1T,
    const float* __restrict__ b1,  const ushort* __restrict__ W2T,
    const float* __restrict__ b2,  ushort* __restrict__ outT,
    char* hb, int w, int g, int c)
{
    const int swz = 16 * (c & 7);

    // ---- layer 1 ----
    f32x4 acc[2][8];
    #pragma unroll
    for (int r = 0; r < 2; ++r)
        #pragma unroll
        for (int mt = 0; mt < 8; ++mt) acc[r][mt] = (f32x4)(0.0f);

    #pragma unroll
    for (int ks = 0; ks < L / 32; ++ks) {
        s16x8 bx[2];
        #pragma unroll
        for (int r = 0; r < 2; ++r) {
            const float* xr = Xt + (size_t)(w * 32 + r * 16 + c) * L + 32 * ks + 8 * g;
            float4 xa = *(const float4*)xr;
            float4 xb = *(const float4*)(xr + 4);
            bx[r][0] = (short)bfbits(san(xa.x)); bx[r][1] = (short)bfbits(san(xa.y));
            bx[r][2] = (short)bfbits(san(xa.z)); bx[r][3] = (short)bfbits(san(xa.w));
            bx[r][4] = (short)bfbits(san(xb.x)); bx[r][5] = (short)bfbits(san(xb.y));
            bx[r][6] = (short)bfbits(san(xb.z)); bx[r][7] = (short)bfbits(san(xb.w));
        }
        #pragma unroll
        for (int mt = 0; mt < 8; ++mt) {
            s16x8 af = *(const s16x8*)(W1T + (16 * mt + c) * L + 32 * ks + 8 * g);
            acc[0][mt] = __builtin_amdgcn_mfma_f32_16x16x32_bf16(af, bx[0], acc[0][mt], 0, 0, 0);
            acc[1][mt] = __builtin_amdgcn_mfma_f32_16x16x32_bf16(af, bx[1], acc[1][mt], 0, 0, 0);
        }
    }

    // bias + relu + pack -> swizzled LDS: H[row r*16+c][hidden 16mt+4g+i]
    #pragma unroll
    for (int r = 0; r < 2; ++r)
        #pragma unroll
        for (int mt = 0; mt < 8; ++mt) {
            float4 bb = *(const float4*)(b1 + 16 * mt + 4 * g);
            ushort4 hv;
            hv.x = bfbits(fmaxf(acc[r][mt][0] + bb.x, 0.0f));
            hv.y = bfbits(fmaxf(acc[r][mt][1] + bb.y, 0.0f));
            hv.z = bfbits(fmaxf(acc[r][mt][2] + bb.z, 0.0f));
            hv.w = bfbits(fmaxf(acc[r][mt][3] + bb.w, 0.0f));
            int off = (32 * mt + 8 * g) ^ swz;
            *(ushort4*)(hb + (r * 16 + c) * 256 + off) = hv;
        }
    __syncthreads();

    // ---- layer 2 ----
    f32x4 acc2[2][8];
    #pragma unroll
    for (int r = 0; r < 2; ++r)
        #pragma unroll
        for (int mt = 0; mt < 8; ++mt) acc2[r][mt] = (f32x4)(0.0f);

    #pragma unroll
    for (int ks = 0; ks < 4; ++ks) {
        s16x8 hf[2];
        #pragma unroll
        for (int r = 0; r < 2; ++r) {
            int off = (64 * ks + 16 * g) ^ swz;
            hf[r] = *(const s16x8*)(hb + (r * 16 + c) * 256 + off);
        }
        #pragma unroll
        for (int mt = 0; mt < 8; ++mt) {
            s16x8 af = *(const s16x8*)(W2T + (16 * mt + c) * HD + 32 * ks + 8 * g);
            acc2[0][mt] = __builtin_amdgcn_mfma_f32_16x16x32_bf16(af, hf[0], acc2[0][mt], 0, 0, 0);
            acc2[1][mt] = __builtin_amdgcn_mfma_f32_16x16x32_bf16(af, hf[1], acc2[1][mt], 0, 0, 0);
        }
    }

    // epilogue: O^T[16mt+4g+i][row] -> out[row][16mt+4g+i]
    #pragma unroll
    for (int r = 0; r < 2; ++r) {
        ushort* orow = outT + (size_t)(w * 32 + r * 16 + c) * HD;
        #pragma unroll
        for (int mt = 0; mt < 8; ++mt) {
            float4 bb = *(const float4*)(b2 + 16 * mt + 4 * g);
            ushort4 ov;
            ov.x = bfbits(san(acc2[r][mt][0] + bb.x));
            ov.y = bfbits(san(acc2[r][mt][1] + bb.y));
            ov.z = bfbits(san(acc2[r][mt][2] + bb.z));
            ov.w = bfbits(san(acc2[r][mt][3] + bb.w));
            *(ushort4*)(orow + 16 * mt + 4 * g) = ov;
        }
    }
}

// Fused MLP over all three inputs: 768 tiles of 128 rows = exactly 3 blocks/CU.
// tiles [0,512): queue -> proj_q; [512,640): latent -> emb_l; [640,768): action -> emb_a
__global__ __launch_bounds__(256) void mlp_fused(
    const float* __restrict__ queue, const float* __restrict__ latent,
    const float* __restrict__ action,
    const ushort* __restrict__ lw1T, const float* __restrict__ lb1,
    const ushort* __restrict__ lw2T, const float* __restrict__ lb2,
    const ushort* __restrict__ aw1T, const float* __restrict__ ab1,
    const ushort* __restrict__ aw2T, const float* __restrict__ ab2,
    ushort* __restrict__ proj_q, ushort* __restrict__ emb_l,
    ushort* __restrict__ emb_a)
{
    __shared__ char hsm[4][8192];
    const int tid  = threadIdx.x;
    const int w    = tid >> 6;
    const int lane = tid & 63;
    const int g    = lane >> 4;
    const int c    = lane & 15;
    char* hb = &hsm[w][0];

    const int tile = blockIdx.x;
    if (tile < 512) {
        mlp_tile<LQ>(queue + (size_t)tile * 128 * LQ, lw1T, lb1, lw2T, lb2,
                     proj_q + (size_t)tile * 128 * HD, hb, w, g, c);
    } else if (tile < 640) {
        int t = tile - 512;
        mlp_tile<LQ>(latent + (size_t)t * 128 * LQ, lw1T, lb1, lw2T, lb2,
                     emb_l + (size_t)t * 128 * HD, hb, w, g, c);
    } else {
        int t = tile - 640;
        mlp_tile<LACT>(action + (size_t)t * 128 * LACT, aw1T, ab1, aw2T, ab2,
                       emb_a + (size_t)t * 128 * HD, hb, w, g, c);
    }
}

// Loss: each wave handles TWO batch rows; lane = (h=row-in-pair, j=negative 0..31).
// All 64 lanes gather a real negative row (256B bf16). Positive logit via
// 32-lane butterfly over per-lane 4-dim partials. Softmax in 32-lane groups.
__global__ __launch_bounds__(256) void loss_kernel(
    const ushort* __restrict__ emb_a, const ushort* __restrict__ emb_l,
    const ushort* __restrict__ proj_q, const int* __restrict__ neg_idx,
    const float* __restrict__ temp_p, float* __restrict__ out)
{
    __shared__ float eas[4][2][128];

    const int tid  = threadIdx.x;
    const int w    = tid >> 6;
    const int lane = tid & 63;
    const int h    = lane >> 5;     // row within pair
    const int j    = lane & 31;     // negative index
    const long b   = (long)blockIdx.x * 8 + w * 2 + h;

    float t = temp_p[0];
    if (!isfinite(t)) t = 0.1f;
    t = fminf(fmaxf(t, 0.01f), 10.0f);
    const float invt = 1.0f / t;

    // stage emb_a row (each lane: 4 dims) + positive-dot partial
    ushort4 av = ((const ushort4*)(emb_a + b * HD))[j];
    ushort4 lv = ((const ushort4*)(emb_l + b * HD))[j];
    float a0 = bf2f(av.x), a1 = bf2f(av.y), a2 = bf2f(av.z), a3 = bf2f(av.w);
    *(float4*)&eas[w][h][4 * j] = make_float4(a0, a1, a2, a3);
    float posp = a0 * bf2f(lv.x) + a1 * bf2f(lv.y) + a2 * bf2f(lv.z) + a3 * bf2f(lv.w);
    const int nidx = neg_idx[b * KNEG + j];
    __syncthreads();

    // gather negative row + dot with staged emb_a (LDS broadcast reads)
    const ushort* nrow = proj_q + (long)nidx * HD;
    float acc = 0.0f;
    #pragma unroll
    for (int i = 0; i < 16; ++i) {
        s16x8 v = *(const s16x8*)(nrow + i * 8);
        #pragma unroll
        for (int k = 0; k < 8; ++k)
            acc = fmaf(bf2f((ushort)v[k]), eas[w][h][i * 8 + k], acc);
    }

    // positive partials -> full dot (32-lane butterfly, stays within half-wave)
    #pragma unroll
    for (int off = 1; off < 32; off <<= 1) posp += __shfl_xor(posp, off, 64);

    float lgp = fminf(fmaxf(san(posp * invt), -20.0f), 20.0f);
    float lgn = fminf(fmaxf(san(acc  * invt), -20.0f), 20.0f);

    float m = fmaxf(lgp, lgn);
    #pragma unroll
    for (int off = 1; off < 32; off <<= 1) m = fmaxf(m, __shfl_xor(m, off, 64));

    float e  = expf(lgn - m);
    float sl = lgn;
    #pragma unroll
    for (int off = 1; off < 32; off <<= 1) {
        e  += __shfl_xor(e, off, 64);
        sl += __shfl_xor(sl, off, 64);
    }
    e  += expf(lgp - m);   // positive term (identical across group)
    sl += lgp;

    float loss = (m + logf(e)) - (1.0f - EPS_) * lgp - EPS_ * (sl * (1.0f / 33.0f));
    loss = fminf(fmaxf(san(loss), -10.0f), 10.0f);

    if (j == 0) out[b] = -loss;
}

extern "C" void kernel_launch(void* const* d_in, const int* in_sizes, int n_in,
                              void* d_out, int out_size, void* d_ws, size_t ws_size,
                              hipStream_t stream) {
    const float* action  = (const float*)d_in[0];
    const float* latent  = (const float*)d_in[1];
    const float* queue   = (const float*)d_in[2];
    const int*   neg_idx = (const int*)  d_in[3];
    const float* a_w1    = (const float*)d_in[4];
    const float* a_b1    = (const float*)d_in[5];
    const float* a_w2    = (const float*)d_in[6];
    const float* a_b2    = (const float*)d_in[7];
    const float* l_w1    = (const float*)d_in[8];
    const float* l_b1    = (const float*)d_in[9];
    const float* l_w2    = (const float*)d_in[10];
    const float* l_b2    = (const float*)d_in[11];
    const float* temp    = (const float*)d_in[12];
    float* out = (float*)d_out;

    // ws: emb_a bf16 4MB | emb_l bf16 4MB | proj_q bf16 16MB | w-transposes 144KB
    ushort* emb_a  = (ushort*)d_ws;
    ushort* emb_l  = emb_a + (size_t)NB * HD;
    ushort* proj_q = emb_l + (size_t)NB * HD;
    ushort* aw1T   = proj_q + (size_t)QN * HD;
    ushort* aw2T   = aw1T + 128 * 64;
    ushort* lw1T   = aw2T + 128 * 128;
    ushort* lw2T   = lw1T + 128 * 256;

    prep_weights<<<288, 256, 0, stream>>>(a_w1, a_w2, l_w1, l_w2, aw1T, aw2T, lw1T, lw2T);
    mlp_fused<<<768, 256, 0, stream>>>(queue, latent, action,
                                       lw1T, l_b1, lw2T, l_b2,
                                       aw1T, a_b1, aw2T, a_b2,
                                       proj_q, emb_l, emb_a);
    loss_kernel<<<NB / 8, 256, 0, stream>>>(emb_a, emb_l, proj_q, neg_idx, temp, out);
}

// Round 4
// 182.695 us; speedup vs baseline: 1.6928x; 1.1372x over previous
//
#include <hip/hip_runtime.h>
#include <hip/hip_bf16.h>

#define NB   16384   // batch B
#define KNEG 32      // negatives per sample
#define LQ   256     // LATENT
#define LACT 64      // ACT
#define HD   128     // H
#define QN   65536   // queue size
#define EPS_ 0.01f   // label smoothing

typedef __attribute__((ext_vector_type(8))) short s16x8;   // 8 bf16 MFMA frag
typedef __attribute__((ext_vector_type(4))) float f32x4;   // MFMA accumulator

#define MFMA __builtin_amdgcn_mfma_f32_16x16x32_bf16

__device__ __forceinline__ float san(float x) { return isfinite(x) ? x : 0.0f; }

// fp32 -> bf16 bits, RNE (inputs pre-sanitized)
__device__ __forceinline__ ushort bfbits(float f) {
    uint u = __builtin_bit_cast(uint, f);
    u += 0x7FFFu + ((u >> 16) & 1u);
    return (ushort)(u >> 16);
}
__device__ __forceinline__ float bf2f(ushort h) {
    uint u = ((uint)h) << 16;
    return __builtin_bit_cast(float, u);
}
__device__ __forceinline__ ushort4 cvt4(float4 v) {
    ushort4 r;
    r.x = bfbits(san(v.x)); r.y = bfbits(san(v.y));
    r.z = bfbits(san(v.z)); r.w = bfbits(san(v.w));
    return r;
}

// One-time weight transpose+bf16: [R][128] -> [128][R]. ushort4 writes (4 rows/thread).
__global__ __launch_bounds__(256) void prep_weights(
    const float* __restrict__ aw1, const float* __restrict__ aw2,
    const float* __restrict__ lw1, const float* __restrict__ lw2,
    ushort* __restrict__ aw1T, ushort* __restrict__ aw2T,
    ushort* __restrict__ lw1T, ushort* __restrict__ lw2T)
{
    int t = blockIdx.x * 256 + threadIdx.x;
    const float* src; ushort* dst; int R;
    if      (t <  2048) {             src = aw1; dst = aw1T; R = 64;  }
    else if (t <  6144) { t -= 2048;  src = aw2; dst = aw2T; R = 128; }
    else if (t < 14336) { t -= 6144;  src = lw1; dst = lw1T; R = 256; }
    else if (t < 18432) { t -= 14336; src = lw2; dst = lw2T; R = 128; }
    else return;
    int c = t & 127, r4 = t >> 7;
    ushort4 o;
    o.x = bfbits(src[(4 * r4 + 0) * 128 + c]);
    o.y = bfbits(src[(4 * r4 + 1) * 128 + c]);
    o.z = bfbits(src[(4 * r4 + 2) * 128 + c]);
    o.w = bfbits(src[(4 * r4 + 3) * 128 + c]);
    *(ushort4*)(dst + c * R + 4 * r4) = o;
}

// MLP v4: weights in VGPR, grid-stride 16-row tiles, reg-prefetch next tile,
// bf16 X staged in LDS (converted once), raw barriers keep prefetch in flight.
// Wave w owns output cols {32w..32w+31} (mt = 2w, 2w+1). 4 waves = all 128.
// Frag maps (16x16x32 bf16): A lane l: A[l&15][(l>>4)*8+i]; B: B[(l>>4)*8+i][l&15];
// D: D[(l>>4)*4+r][l&15]. Swizzle: byte ^ ((row&SWZM)<<4) on X and H tiles.
template<int L>
__global__ __launch_bounds__(256, 3) void mlp_v4(
    const float* __restrict__ X0, const float* __restrict__ X1, int rows0,
    ushort* __restrict__ out0, ushort* __restrict__ out1,
    const ushort* __restrict__ W1T, const float* __restrict__ b1,
    const ushort* __restrict__ W2T, const float* __restrict__ b2,
    int ntiles)
{
    constexpr int KS1  = L / 32;
    constexpr int SWZM = (L == 64) ? 7 : 15;
    constexpr int PFN  = (L == 64) ? 1 : 4;    // float4 prefetch regs per thread

    __shared__ __align__(16) char xb[16 * 2 * L];   // bf16 X tile [16][L]
    __shared__ __align__(16) char hb[16 * 256];     // bf16 H tile [16][128]

    const int tid  = threadIdx.x;
    const int w    = tid >> 6;
    const int lane = tid & 63;
    const int g    = lane >> 4;
    const int c    = lane & 15;
    const int mtg0 = 2 * w, mtg1 = 2 * w + 1;

    // ---- preload weights into VGPRs (reused for every tile) ----
    s16x8 w1f[KS1][2], w2f[4][2];
    #pragma unroll
    for (int ks = 0; ks < KS1; ++ks) {
        w1f[ks][0] = *(const s16x8*)(W1T + (16 * mtg0 + c) * L + 32 * ks + 8 * g);
        w1f[ks][1] = *(const s16x8*)(W1T + (16 * mtg1 + c) * L + 32 * ks + 8 * g);
    }
    #pragma unroll
    for (int ks = 0; ks < 4; ++ks) {
        w2f[ks][0] = *(const s16x8*)(W2T + (16 * mtg0 + c) * HD + 32 * ks + 8 * g);
        w2f[ks][1] = *(const s16x8*)(W2T + (16 * mtg1 + c) * HD + 32 * ks + 8 * g);
    }

    // staging geometry: thread covers row srow, elems scol*(L/16) .. +L/16-1
    const int srow = tid >> 4;   // 0..15
    const int scol = tid & 15;

    float4 pf[PFN];

    auto src_ptr = [&](int tt) -> const float* {
        int r0 = tt * 16;
        const float* base = (r0 < rows0) ? X0 + (size_t)r0 * L
                                         : X1 + (size_t)(r0 - rows0) * L;
        return base + srow * L + scol * (L / 16);
    };

    int tt = blockIdx.x;
    if (tt < ntiles) {
        const float* p = src_ptr(tt);
        #pragma unroll
        for (int q = 0; q < PFN; ++q) pf[q] = ((const float4*)p)[q];
    }

    for (; tt < ntiles; tt += gridDim.x) {
        // ---- stage current tile (cvt fp32->bf16, swizzled LDS write) ----
        if constexpr (L == 256) {
            ushort4 q0 = cvt4(pf[0]), q1 = cvt4(pf[1]);
            ushort4 q2 = cvt4(pf[2]), q3 = cvt4(pf[3]);
            s16x8 v0 = { (short)q0.x, (short)q0.y, (short)q0.z, (short)q0.w,
                         (short)q1.x, (short)q1.y, (short)q1.z, (short)q1.w };
            s16x8 v1 = { (short)q2.x, (short)q2.y, (short)q2.z, (short)q2.w,
                         (short)q3.x, (short)q3.y, (short)q3.z, (short)q3.w };
            int a  = srow * 512 + scol * 32;
            int sz = srow << 4;
            *(s16x8*)(xb + ( a        ^ sz)) = v0;
            *(s16x8*)(xb + ((a + 16)  ^ sz)) = v1;
        } else {
            ushort4 q0 = cvt4(pf[0]);
            int a  = srow * 128 + scol * 8;
            int sz = (srow & 7) << 4;
            *(ushort4*)(xb + (a ^ sz)) = q0;
        }
        asm volatile("s_waitcnt lgkmcnt(0)" ::: "memory");
        __builtin_amdgcn_s_barrier();          // xb ready

        // ---- issue prefetch for next tile (stays in flight across barriers) ----
        int nt = tt + gridDim.x;
        if (nt < ntiles) {
            const float* p = src_ptr(nt);
            #pragma unroll
            for (int q = 0; q < PFN; ++q) pf[q] = ((const float4*)p)[q];
        }

        // ---- layer 1 ----
        f32x4 acc0 = (f32x4)(0.0f), acc1 = (f32x4)(0.0f);
        #pragma unroll
        for (int ks = 0; ks < KS1; ++ks) {
            int a = (c * 2 * L + 64 * ks + 16 * g) ^ ((c & SWZM) << 4);
            s16x8 bx = *(const s16x8*)(xb + a);
            acc0 = MFMA(w1f[ks][0], bx, acc0, 0, 0, 0);
            acc1 = MFMA(w1f[ks][1], bx, acc1, 0, 0, 0);
        }

        // ---- bias+relu -> H tile ----
        {
            float4 bb0 = *(const float4*)(b1 + 16 * mtg0 + 4 * g);
            float4 bb1v = *(const float4*)(b1 + 16 * mtg1 + 4 * g);
            ushort4 h0, h1;
            h0.x = bfbits(fmaxf(acc0[0] + bb0.x, 0.0f));
            h0.y = bfbits(fmaxf(acc0[1] + bb0.y, 0.0f));
            h0.z = bfbits(fmaxf(acc0[2] + bb0.z, 0.0f));
            h0.w = bfbits(fmaxf(acc0[3] + bb0.w, 0.0f));
            h1.x = bfbits(fmaxf(acc1[0] + bb1v.x, 0.0f));
            h1.y = bfbits(fmaxf(acc1[1] + bb1v.y, 0.0f));
            h1.z = bfbits(fmaxf(acc1[2] + bb1v.z, 0.0f));
            h1.w = bfbits(fmaxf(acc1[3] + bb1v.w, 0.0f));
            *(ushort4*)(hb + ((c * 256 + (16 * mtg0 + 4 * g) * 2) ^ (c << 4))) = h0;
            *(ushort4*)(hb + ((c * 256 + (16 * mtg1 + 4 * g) * 2) ^ (c << 4))) = h1;
        }
        asm volatile("s_waitcnt lgkmcnt(0)" ::: "memory");
        __builtin_amdgcn_s_barrier();          // hb ready

        // ---- layer 2 ----
        f32x4 d0 = (f32x4)(0.0f), d1 = (f32x4)(0.0f);
        #pragma unroll
        for (int ks = 0; ks < 4; ++ks) {
            int a = (c * 256 + 64 * ks + 16 * g) ^ (c << 4);
            s16x8 hx = *(const s16x8*)(hb + a);
            d0 = MFMA(w2f[ks][0], hx, d0, 0, 0, 0);
            d1 = MFMA(w2f[ks][1], hx, d1, 0, 0, 0);
        }

        // ---- epilogue ----
        {
            int r0 = tt * 16;
            ushort* orow = ((r0 < rows0) ? out0 + (size_t)r0 * HD
                                         : out1 + (size_t)(r0 - rows0) * HD)
                           + (size_t)c * HD;
            float4 c0 = *(const float4*)(b2 + 16 * mtg0 + 4 * g);
            float4 c1 = *(const float4*)(b2 + 16 * mtg1 + 4 * g);
            ushort4 o0, o1;
            o0.x = bfbits(san(d0[0] + c0.x));
            o0.y = bfbits(san(d0[1] + c0.y));
            o0.z = bfbits(san(d0[2] + c0.z));
            o0.w = bfbits(san(d0[3] + c0.w));
            o1.x = bfbits(san(d1[0] + c1.x));
            o1.y = bfbits(san(d1[1] + c1.y));
            o1.z = bfbits(san(d1[2] + c1.z));
            o1.w = bfbits(san(d1[3] + c1.w));
            *(ushort4*)(orow + 16 * mtg0 + 4 * g) = o0;
            *(ushort4*)(orow + 16 * mtg1 + 4 * g) = o1;
        }
        // loop back: stage(t+1) writes xb only after all waves passed the hb
        // barrier (their xb reads finished before it) -> 2 barriers/tile total.
    }
}

// Loss: wave = 2 batch rows x 32 negatives; batched gather preloads + 4 accs.
__global__ __launch_bounds__(256, 6) void loss_v2(
    const ushort* __restrict__ emb_a, const ushort* __restrict__ emb_l,
    const ushort* __restrict__ proj_q, const int* __restrict__ neg_idx,
    const float* __restrict__ temp_p, float* __restrict__ out)
{
    __shared__ float eas[4][2][128];

    const int tid  = threadIdx.x;
    const int w    = tid >> 6;
    const int lane = tid & 63;
    const int h    = lane >> 5;
    const int j    = lane & 31;
    const long b   = (long)blockIdx.x * 8 + w * 2 + h;

    float t = temp_p[0];
    if (!isfinite(t)) t = 0.1f;
    t = fminf(fmaxf(t, 0.01f), 10.0f);
    const float invt = 1.0f / t;

    ushort4 av = ((const ushort4*)(emb_a + b * HD))[j];
    ushort4 lv = ((const ushort4*)(emb_l + b * HD))[j];
    float a0 = bf2f(av.x), a1 = bf2f(av.y), a2 = bf2f(av.z), a3 = bf2f(av.w);
    *(float4*)&eas[w][h][4 * j] = make_float4(a0, a1, a2, a3);
    float posp = a0 * bf2f(lv.x) + a1 * bf2f(lv.y) + a2 * bf2f(lv.z) + a3 * bf2f(lv.w);
    const int ni = neg_idx[b * KNEG + j];
    __syncthreads();

    const ushort* nrow = proj_q + (long)ni * HD;
    float ac0 = 0.0f, ac1 = 0.0f, ac2 = 0.0f, ac3 = 0.0f;
    #pragma unroll
    for (int bt = 0; bt < 2; ++bt) {
        s16x8 v[8];
        #pragma unroll
        for (int q = 0; q < 8; ++q) v[q] = ((const s16x8*)nrow)[bt * 8 + q];
        #pragma unroll
        for (int q = 0; q < 8; ++q) {
            float4 ea = *(const float4*)&eas[w][h][(bt * 8 + q) * 8];
            float4 eb = *(const float4*)&eas[w][h][(bt * 8 + q) * 8 + 4];
            ac0 = fmaf(bf2f((ushort)v[q][0]), ea.x, ac0);
            ac1 = fmaf(bf2f((ushort)v[q][1]), ea.y, ac1);
            ac2 = fmaf(bf2f((ushort)v[q][2]), ea.z, ac2);
            ac3 = fmaf(bf2f((ushort)v[q][3]), ea.w, ac3);
            ac0 = fmaf(bf2f((ushort)v[q][4]), eb.x, ac0);
            ac1 = fmaf(bf2f((ushort)v[q][5]), eb.y, ac1);
            ac2 = fmaf(bf2f((ushort)v[q][6]), eb.z, ac2);
            ac3 = fmaf(bf2f((ushort)v[q][7]), eb.w, ac3);
        }
    }
    float acc = (ac0 + ac1) + (ac2 + ac3);

    // positive partials -> full dot (32-lane butterfly)
    #pragma unroll
    for (int off = 1; off < 32; off <<= 1) posp += __shfl_xor(posp, off, 64);

    float lgp = fminf(fmaxf(san(posp * invt), -20.0f), 20.0f);
    float lgn = fminf(fmaxf(san(acc  * invt), -20.0f), 20.0f);

    float m = fmaxf(lgp, lgn);
    #pragma unroll
    for (int off = 1; off < 32; off <<= 1) m = fmaxf(m, __shfl_xor(m, off, 64));

    float e  = expf(lgn - m);
    float sl = lgn;
    #pragma unroll
    for (int off = 1; off < 32; off <<= 1) {
        e  += __shfl_xor(e, off, 64);
        sl += __shfl_xor(sl, off, 64);
    }
    e  += expf(lgp - m);
    sl += lgp;

    float loss = (m + logf(e)) - (1.0f - EPS_) * lgp - EPS_ * (sl * (1.0f / 33.0f));
    loss = fminf(fmaxf(san(loss), -10.0f), 10.0f);

    if (j == 0) out[b] = -loss;
}

extern "C" void kernel_launch(void* const* d_in, const int* in_sizes, int n_in,
                              void* d_out, int out_size, void* d_ws, size_t ws_size,
                              hipStream_t stream) {
    const float* action  = (const float*)d_in[0];
    const float* latent  = (const float*)d_in[1];
    const float* queue   = (const float*)d_in[2];
    const int*   neg_idx = (const int*)  d_in[3];
    const float* a_w1    = (const float*)d_in[4];
    const float* a_b1    = (const float*)d_in[5];
    const float* a_w2    = (const float*)d_in[6];
    const float* a_b2    = (const float*)d_in[7];
    const float* l_w1    = (const float*)d_in[8];
    const float* l_b1    = (const float*)d_in[9];
    const float* l_w2    = (const float*)d_in[10];
    const float* l_b2    = (const float*)d_in[11];
    const float* temp    = (const float*)d_in[12];
    float* out = (float*)d_out;

    // ws: emb_a bf16 4MB | emb_l bf16 4MB | proj_q bf16 16MB | weight transposes
    ushort* emb_a  = (ushort*)d_ws;
    ushort* emb_l  = emb_a + (size_t)NB * HD;
    ushort* proj_q = emb_l + (size_t)NB * HD;
    ushort* aw1T   = proj_q + (size_t)QN * HD;
    ushort* aw2T   = aw1T + 128 * 64;
    ushort* lw1T   = aw2T + 128 * 128;
    ushort* lw2T   = lw1T + 128 * 256;

    prep_weights<<<72, 256, 0, stream>>>(a_w1, a_w2, l_w1, l_w2,
                                         aw1T, aw2T, lw1T, lw2T);
    // queue (65536 rows) + latent (16384 rows), 16-row tiles, grid-stride
    mlp_v4<LQ><<<768, 256, 0, stream>>>(queue, latent, QN, proj_q, emb_l,
                                        lw1T, l_b1, lw2T, l_b2,
                                        (QN + NB) / 16);
    // action (16384 rows)
    mlp_v4<LACT><<<768, 256, 0, stream>>>(action, action, NB, emb_a, emb_a,
                                          aw1T, a_b1, aw2T, a_b2,
                                          NB / 16);
    loss_v2<<<NB / 8, 256, 0, stream>>>(emb_a, emb_l, proj_q, neg_idx, temp, out);
}